// Round 8
// baseline (31.857 us; speedup 1.0000x reference)
//
#include <hip/hip_runtime.h>

#define BLOCK 256

// bs[g] = first node index with batch >= g, for g in [0, G]; derived from
// adjacent-pair boundaries of the sorted batch array (coalesced single pass,
// each bs[g] written by exactly one thread).
__global__ __launch_bounds__(BLOCK) void seg_starts(
    const int* __restrict__ batch, int n, int G, int* __restrict__ bs)
{
    int i = blockIdx.x * blockDim.x + threadIdx.x;
    if (i >= n) return;
    int lane = threadIdx.x & 63;
    int b = batch[i];
    int p = __shfl_up(b, 1);
    if (lane == 0) p = (i == 0) ? -1 : batch[i - 1];
    for (int g = p + 1; g <= b; ++g) bs[g] = i;       // head + interior boundaries
    if (i == n - 1) {
        for (int g = b + 1; g <= G; ++g) bs[g] = n;   // tail (incl. trailing empties)
    }
}

// One wave per graph: sum its contiguous node range, butterfly-reduce,
// lane 0 stores. No atomics, no zero-init, no key handling.
// Model collapse (verified R7): out1 = k1*s*v is parallel to v so all
// cross(out,v) terms vanish; y = (C*s^4)*(W@p + u) + fc_b,
// W = fc_w@lin_w, u = fc_w@lin_b, C = k1*la0*la1*la2.
__global__ __launch_bounds__(BLOCK) void e3nn_graphs(
    const int* __restrict__ z, const float* __restrict__ pos,
    const float* __restrict__ embed,
    const float* __restrict__ lin_w, const float* __restrict__ lin_b,
    const float* __restrict__ tp1_w, const float* __restrict__ tp2_w,
    const float* __restrict__ tp3_w, const float* __restrict__ gate_w,
    const float* __restrict__ fc_w, const float* __restrict__ fc_b,
    const int* __restrict__ bs,
    float* __restrict__ out, int G)
{
    const int w    = (blockIdx.x * BLOCK + threadIdx.x) >> 6;   // wave id = graph id
    const int lane = threadIdx.x & 63;
    if (w >= G) return;

    const int s = bs[w];
    const int e = bs[w + 1];

    // constants / collapsed weights (uniform scalar loads, L1-resident)
    const float C01 = 0.57735026918962576f;   // 1/sqrt(3)
    const float PW2 = 1.2247448713915890f;    // sqrt(1.5)
    const float k1  = (tp1_w[0] + tp1_w[1]) * C01;
    const float la0 = PW2 * tp2_w[0] * C01;
    const float la1 = PW2 * tp3_w[0] * C01;
    const float la2 = PW2 * gate_w[0] * C01;
    const float C   = k1 * la0 * la1 * la2;

    float lw[9], fw[9], lbv[3], fbv[3];
#pragma unroll
    for (int i = 0; i < 9; ++i) { lw[i] = lin_w[i]; fw[i] = fc_w[i]; }
#pragma unroll
    for (int i = 0; i < 3; ++i) { lbv[i] = lin_b[i]; fbv[i] = fc_b[i]; }

    float W[9], u[3];
#pragma unroll
    for (int r = 0; r < 3; ++r) {
#pragma unroll
        for (int cc = 0; cc < 3; ++cc)
            W[r*3+cc] = fw[r*3+0]*lw[0*3+cc] + fw[r*3+1]*lw[1*3+cc] + fw[r*3+2]*lw[2*3+cc];
        u[r] = fw[r*3+0]*lbv[0] + fw[r*3+1]*lbv[1] + fw[r*3+2]*lbv[2];
    }

    float rx = 0.f, ry = 0.f, rz = 0.f;

    for (int base = s; base < e; base += 64) {
        int i = base + lane;
        if (i < e) {
            float sE = embed[z[i]];
            float s2 = sE * sE;
            float t  = C * (s2 * s2);                 // C * s^4

            float X = pos[3*i], Y = pos[3*i+1], Z = pos[3*i+2];
            float gx = W[0]*X + W[1]*Y + W[2]*Z + u[0];
            float gy = W[3]*X + W[4]*Y + W[5]*Z + u[1];
            float gz = W[6]*X + W[7]*Y + W[8]*Z + u[2];

            rx += t * gx + fbv[0];
            ry += t * gy + fbv[1];
            rz += t * gz + fbv[2];
        }
    }

    // 64-lane butterfly sum
#pragma unroll
    for (int off = 1; off < 64; off <<= 1) {
        rx += __shfl_xor(rx, off);
        ry += __shfl_xor(ry, off);
        rz += __shfl_xor(rz, off);
    }

    if (lane == 0) {
        out[3*w + 0] = rx;
        out[3*w + 1] = ry;
        out[3*w + 2] = rz;      // empty graph (s==e) -> zeros, exactly once
    }
}

extern "C" void kernel_launch(void* const* d_in, const int* in_sizes, int n_in,
                              void* d_out, int out_size, void* d_ws, size_t ws_size,
                              hipStream_t stream) {
    const int*   z     = (const int*)  d_in[0];
    const float* pos   = (const float*)d_in[1];
    const int*   batch = (const int*)  d_in[2];
    const float* embed = (const float*)d_in[3];
    const float* lin_w = (const float*)d_in[4];
    const float* lin_b = (const float*)d_in[5];
    const float* tp1_w = (const float*)d_in[6];
    const float* tp2_w = (const float*)d_in[7];
    const float* tp3_w = (const float*)d_in[8];
    const float* gate_w= (const float*)d_in[9];
    const float* fc_w  = (const float*)d_in[10];
    const float* fc_b  = (const float*)d_in[11];
    float* out = (float*)d_out;

    int n = in_sizes[0];
    int G = out_size / 3;

    int* bs = (int*)d_ws;                       // (G+1) ints

    seg_starts<<<(n + BLOCK - 1) / BLOCK, BLOCK, 0, stream>>>(batch, n, G, bs);

    int waves_blocks = (G * 64 + BLOCK - 1) / BLOCK;   // one wave per graph
    e3nn_graphs<<<waves_blocks, BLOCK, 0, stream>>>(
        z, pos, embed, lin_w, lin_b,
        tp1_w, tp2_w, tp3_w, gate_w, fc_w, fc_b, bs, out, G);
}